// Round 2
// baseline (1354.452 us; speedup 1.0000x reference)
//
#include <hip/hip_runtime.h>
#include <hip/hip_bf16.h>

#define N_NODES   50000
#define N_EDGES   640000
#define NODE_DIM  16
#define HIDDEN    128
#define LATENT    64
#define MAX_NODES 100
#define NUM_GRAPHS 256

// ---------------------------------------------------------------------------
// Edge scatter-add, DIM=16 (layer 1): agg[dst[e]][d] += x[src[e]][d]
// ---------------------------------------------------------------------------
__global__ void scatter_add16_kernel(const float* __restrict__ x,
                                     const int* __restrict__ src,
                                     const int* __restrict__ dst,
                                     float* __restrict__ agg) {
    const long total = (long)N_EDGES * NODE_DIM;
    for (long i = blockIdx.x * (long)blockDim.x + threadIdx.x; i < total;
         i += (long)gridDim.x * blockDim.x) {
        const int e = (int)(i >> 4);
        const int d = (int)(i & 15);
        atomicAdd(&agg[(long)dst[e] * NODE_DIM + d], x[(long)src[e] * NODE_DIM + d]);
    }
}

// ---------------------------------------------------------------------------
// Edge scatter-add, DIM=128 (layer 2), float4 gather: one thread per
// (edge, 4-dim group). Wave = 2 edges x 512B rows, fully coalesced gather.
// ---------------------------------------------------------------------------
__global__ void scatter_add128_kernel(const float* __restrict__ x,
                                      const int* __restrict__ src,
                                      const int* __restrict__ dst,
                                      float* __restrict__ agg) {
    const long total = (long)N_EDGES * (HIDDEN / 4);
    for (long i = blockIdx.x * (long)blockDim.x + threadIdx.x; i < total;
         i += (long)gridDim.x * blockDim.x) {
        const int e  = (int)(i >> 5);
        const int d4 = (int)(i & 31) << 2;
        const float4 v = *(const float4*)&x[(long)src[e] * HIDDEN + d4];
        float* p = &agg[(long)dst[e] * HIDDEN + d4];
        atomicAdd(p + 0, v.x);
        atomicAdd(p + 1, v.y);
        atomicAdd(p + 2, v.z);
        atomicAdd(p + 3, v.w);
    }
}

// ---------------------------------------------------------------------------
// GIN MLP: out = relu( relu(in @ wa + ba) @ wb + bb ),  in: N_NODES x K0
// ---------------------------------------------------------------------------
template <int K0, int NB>
__global__ void gin_mlp_kernel(const float* __restrict__ in,
                               const float* __restrict__ wa, const float* __restrict__ ba,
                               const float* __restrict__ wb, const float* __restrict__ bb,
                               float* __restrict__ out) {
    __shared__ float s_in[NB][K0];
    __shared__ float s_mid[NB][HIDDEN];
    const int d  = threadIdx.x;          // 0..127
    const int n0 = blockIdx.x * NB;

    for (int idx = threadIdx.x; idx < NB * K0; idx += blockDim.x) {
        const int i = idx / K0;
        const int k = idx - i * K0;
        const int n = n0 + i;
        s_in[i][k] = (n < N_NODES) ? in[(long)n * K0 + k] : 0.f;
    }
    __syncthreads();

    float acc[NB];
    {
        const float bias = ba[d];
        #pragma unroll
        for (int i = 0; i < NB; ++i) acc[i] = bias;
        for (int k = 0; k < K0; ++k) {
            const float w = wa[k * HIDDEN + d];
            #pragma unroll
            for (int i = 0; i < NB; ++i) acc[i] += s_in[i][k] * w;
        }
        #pragma unroll
        for (int i = 0; i < NB; ++i) s_mid[i][d] = fmaxf(acc[i], 0.f);
    }
    __syncthreads();
    {
        const float bias = bb[d];
        #pragma unroll
        for (int i = 0; i < NB; ++i) acc[i] = bias;
        for (int k = 0; k < HIDDEN; ++k) {
            const float w = wb[k * HIDDEN + d];
            #pragma unroll
            for (int i = 0; i < NB; ++i) acc[i] += s_mid[i][k] * w;
        }
        #pragma unroll
        for (int i = 0; i < NB; ++i) {
            const int n = n0 + i;
            if (n < N_NODES) out[(long)n * HIDDEN + d] = fmaxf(acc[i], 0.f);
        }
    }
}

// ---------------------------------------------------------------------------
// Mean pooling over sorted batch ids: run-length accumulate, few atomics.
// ---------------------------------------------------------------------------
__global__ void pool_kernel(const float* __restrict__ h,
                            const int* __restrict__ batch,
                            float* __restrict__ summed,   // NUM_GRAPHS x HIDDEN
                            float* __restrict__ counts) { // NUM_GRAPHS
    const int NPB = 128;
    const int n0 = blockIdx.x * NPB;
    if (n0 >= N_NODES) return;
    const int nend = min(n0 + NPB, N_NODES);
    const int d = threadIdx.x;

    int cur = batch[n0];
    float acc = 0.f;
    int cnt = 0;
    for (int n = n0; n < nend; ++n) {
        const int g = batch[n];
        if (g != cur) {
            atomicAdd(&summed[cur * HIDDEN + d], acc);
            if (d == 0) atomicAdd(&counts[cur], (float)cnt);
            acc = 0.f; cnt = 0; cur = g;
        }
        acc += h[(long)n * HIDDEN + d];
        ++cnt;
    }
    atomicAdd(&summed[cur * HIDDEN + d], acc);
    if (d == 0) atomicAdd(&counts[cur], (float)cnt);
}

// ---------------------------------------------------------------------------
// Per-graph head: pooled -> mu, logvar, z -> hd (decoder trunk).
// ---------------------------------------------------------------------------
__global__ void head_kernel(const float* __restrict__ summed,
                            const float* __restrict__ counts,
                            const float* __restrict__ eps,
                            const float* __restrict__ wmu, const float* __restrict__ bmu,
                            const float* __restrict__ wlv, const float* __restrict__ blv,
                            const float* __restrict__ wd1, const float* __restrict__ bd1,
                            const float* __restrict__ wd2, const float* __restrict__ bd2,
                            float* __restrict__ out_mu, float* __restrict__ out_lv,
                            float* __restrict__ hd) {
    const int g = blockIdx.x;
    const int d = threadIdx.x;
    __shared__ float s_pool[HIDDEN];
    __shared__ float s_z[LATENT];
    __shared__ float s_h1[HIDDEN];

    const float cnt = fmaxf(counts[g], 1.f);
    s_pool[d] = summed[g * HIDDEN + d] / cnt;
    __syncthreads();

    if (d < LATENT) {
        float m = bmu[d], lv = blv[d];
        for (int k = 0; k < HIDDEN; ++k) {
            const float p = s_pool[k];
            m  += p * wmu[k * LATENT + d];
            lv += p * wlv[k * LATENT + d];
        }
        lv = fminf(fmaxf(lv, -5.f), 5.f);
        out_mu[g * LATENT + d] = m;
        out_lv[g * LATENT + d] = lv;
        s_z[d] = m + eps[g * LATENT + d] * expf(0.5f * lv);
    }
    __syncthreads();
    {
        float a = bd1[d];
        for (int k = 0; k < LATENT; ++k) a += s_z[k] * wd1[k * HIDDEN + d];
        s_h1[d] = fmaxf(a, 0.f);
    }
    __syncthreads();
    {
        float a = bd2[d];
        for (int k = 0; k < HIDDEN; ++k) a += s_h1[k] * wd2[k * HIDDEN + d];
        hd[g * HIDDEN + d] = a;
    }
}

// ---------------------------------------------------------------------------
// Decoder GEMM: raw[256 x N] = hd[256 x 128] @ W[128 x N] + bias
// 16 graphs per block (LDS), one output column per thread -> 16 independent
// accumulators per thread, 16 FMA per W-load.
// ---------------------------------------------------------------------------
__global__ void decoder_gemm_kernel(const float* __restrict__ hd,
                                    const float* __restrict__ W,
                                    const float* __restrict__ bias,
                                    float* __restrict__ raw, int N) {
    const int GB = 16;
    const int o  = blockIdx.x * blockDim.x + threadIdx.x;  // output column
    const int g0 = blockIdx.y * GB;
    __shared__ float s_hd[GB][HIDDEN];

    for (int idx = threadIdx.x; idx < GB * HIDDEN; idx += blockDim.x) {
        const int g = idx >> 7;
        const int k = idx & 127;
        s_hd[g][k] = hd[(long)(g0 + g) * HIDDEN + k];
    }
    __syncthreads();
    if (o >= N) return;

    float acc[GB];
    const float bv = bias[o];
    #pragma unroll
    for (int g = 0; g < GB; ++g) acc[g] = bv;

    for (int k = 0; k < HIDDEN; ++k) {
        const float w = W[(long)k * N + o];
        #pragma unroll
        for (int g = 0; g < GB; ++g) acc[g] += s_hd[g][k] * w;
    }
    #pragma unroll
    for (int g = 0; g < GB; ++g)
        raw[(long)(g0 + g) * N + o] = acc[g];
}

// ---------------------------------------------------------------------------
// adj epilogue: out = clip(0.5*(raw + raw^T), -10, 10), diag = -10.
// ---------------------------------------------------------------------------
__global__ void adj_sym_kernel(const float* __restrict__ raw,
                               float* __restrict__ out_adj) {
    const int g = blockIdx.x;
    const int tid = threadIdx.x;
    __shared__ float s_a[MAX_NODES * MAX_NODES];  // 40KB
    const float* r = raw + (long)g * MAX_NODES * MAX_NODES;

    for (int o = tid; o < MAX_NODES * MAX_NODES; o += blockDim.x) s_a[o] = r[o];
    __syncthreads();

    float* w = out_adj + (long)g * MAX_NODES * MAX_NODES;
    for (int o = tid; o < MAX_NODES * MAX_NODES; o += blockDim.x) {
        const int i = o / MAX_NODES;
        const int j = o - i * MAX_NODES;
        float v;
        if (i == j) v = -10.f;
        else        v = fminf(fmaxf(0.5f * (s_a[o] + s_a[j * MAX_NODES + i]), -10.f), 10.f);
        w[o] = v;
    }
}

// ---------------------------------------------------------------------------
// node-feature epilogue: softmax over last dim (16), one thread per (g,node).
// ---------------------------------------------------------------------------
__global__ void nf_softmax_kernel(const float* __restrict__ raw,
                                  float* __restrict__ out_nf) {
    const int idx = blockIdx.x * blockDim.x + threadIdx.x;  // (g, m)
    if (idx >= NUM_GRAPHS * MAX_NODES) return;
    const float* r = raw + (long)idx * NODE_DIM;

    float mx = -1e30f;
    #pragma unroll
    for (int d = 0; d < NODE_DIM; ++d) mx = fmaxf(mx, r[d]);
    float e[NODE_DIM];
    float s = 0.f;
    #pragma unroll
    for (int d = 0; d < NODE_DIM; ++d) { e[d] = expf(r[d] - mx); s += e[d]; }
    const float inv = 1.f / s;
    float* w = out_nf + (long)idx * NODE_DIM;
    #pragma unroll
    for (int d = 0; d < NODE_DIM; ++d) w[d] = e[d] * inv;
}

// ---------------------------------------------------------------------------
extern "C" void kernel_launch(void* const* d_in, const int* in_sizes, int n_in,
                              void* d_out, int out_size, void* d_ws, size_t ws_size,
                              hipStream_t stream) {
    const float* x    = (const float*)d_in[0];
    const int*   edge = (const int*)d_in[1];
    const int*   src  = edge;
    const int*   dst  = edge + N_EDGES;
    const int*   batch = (const int*)d_in[2];
    const float* eps  = (const float*)d_in[3];
    const float* w1a = (const float*)d_in[4],  *b1a = (const float*)d_in[5];
    const float* w1b = (const float*)d_in[6],  *b1b = (const float*)d_in[7];
    const float* w2a = (const float*)d_in[8],  *b2a = (const float*)d_in[9];
    const float* w2b = (const float*)d_in[10], *b2b = (const float*)d_in[11];
    const float* wmu = (const float*)d_in[12], *bmu = (const float*)d_in[13];
    const float* wlv = (const float*)d_in[14], *blv = (const float*)d_in[15];
    const float* wd1 = (const float*)d_in[16], *bd1 = (const float*)d_in[17];
    const float* wd2 = (const float*)d_in[18], *bd2 = (const float*)d_in[19];
    const float* wn  = (const float*)d_in[20], *bn  = (const float*)d_in[21];
    const float* we  = (const float*)d_in[22], *be  = (const float*)d_in[23];

    float* out = (float*)d_out;
    float* out_adj = out;                                                  // 2,560,000
    float* out_nf  = out + (long)NUM_GRAPHS * MAX_NODES * MAX_NODES;       // 409,600
    float* out_mu  = out_nf + (long)NUM_GRAPHS * MAX_NODES * NODE_DIM;     // 16,384
    float* out_lv  = out_mu + NUM_GRAPHS * LATENT;                         // 16,384

    float* ws = (float*)d_ws;
    float* agg1   = ws;                                // 800,000
    float* h1     = agg1 + (long)N_NODES * NODE_DIM;   // 6,400,000
    float* agg2   = h1 + (long)N_NODES * HIDDEN;       // 6,400,000
    float* summed = agg2 + (long)N_NODES * HIDDEN;     // 32,768
    float* counts = summed + NUM_GRAPHS * HIDDEN;      // 256
    float* hd     = counts + NUM_GRAPHS;               // 32,768
    float* h2     = h1;    // reuse: h1 dead once agg2 built
    float* raw_adj = agg2; // reuse: agg2 dead after gin_mlp2  (2,560,000)
    float* raw_nf  = agg2 + (long)NUM_GRAPHS * MAX_NODES * MAX_NODES; // 409,600

    // ---- GIN layer 1 ----
    hipMemcpyAsync(agg1, x, sizeof(float) * (size_t)N_NODES * NODE_DIM,
                   hipMemcpyDeviceToDevice, stream);
    scatter_add16_kernel<<<2048, 256, 0, stream>>>(x, src, dst, agg1);
    gin_mlp_kernel<NODE_DIM, 8><<<(N_NODES + 7) / 8, 128, 0, stream>>>(
        agg1, w1a, b1a, w1b, b1b, h1);

    // ---- GIN layer 2 ----
    hipMemcpyAsync(agg2, h1, sizeof(float) * (size_t)N_NODES * HIDDEN,
                   hipMemcpyDeviceToDevice, stream);
    scatter_add128_kernel<<<2048, 256, 0, stream>>>(h1, src, dst, agg2);
    gin_mlp_kernel<HIDDEN, 8><<<(N_NODES + 7) / 8, 128, 0, stream>>>(
        agg2, w2a, b2a, w2b, b2b, h2);

    // ---- mean pool ----
    hipMemsetAsync(summed, 0, sizeof(float) * (NUM_GRAPHS * HIDDEN + NUM_GRAPHS), stream);
    pool_kernel<<<(N_NODES + 127) / 128, 128, 0, stream>>>(h2, batch, summed, counts);

    // ---- heads + reparam + decoder trunk ----
    head_kernel<<<NUM_GRAPHS, 128, 0, stream>>>(summed, counts, eps,
                                                wmu, bmu, wlv, blv,
                                                wd1, bd1, wd2, bd2,
                                                out_mu, out_lv, hd);

    // ---- decoder GEMMs ----
    {
        dim3 grid_adj((MAX_NODES * MAX_NODES + 255) / 256, NUM_GRAPHS / 16);
        decoder_gemm_kernel<<<grid_adj, 256, 0, stream>>>(hd, we, be, raw_adj,
                                                          MAX_NODES * MAX_NODES);
        dim3 grid_nf((MAX_NODES * NODE_DIM + 255) / 256, NUM_GRAPHS / 16);
        decoder_gemm_kernel<<<grid_nf, 256, 0, stream>>>(hd, wn, bn, raw_nf,
                                                         MAX_NODES * NODE_DIM);
    }

    // ---- epilogues ----
    adj_sym_kernel<<<NUM_GRAPHS, 512, 0, stream>>>(raw_adj, out_adj);
    nf_softmax_kernel<<<(NUM_GRAPHS * MAX_NODES + 255) / 256, 256, 0, stream>>>(
        raw_nf, out_nf);
}

// Round 3
// 534.803 us; speedup vs baseline: 2.5326x; 2.5326x over previous
//
#include <hip/hip_runtime.h>
#include <hip/hip_bf16.h>

#define N_NODES   50000
#define N_EDGES   640000
#define NODE_DIM  16
#define HIDDEN    128
#define LATENT    64
#define MAX_NODES 100
#define NUM_GRAPHS 256

// ---------------------------------------------------------------------------
// Edge scatter-add: agg[dst[e]][d] += x[src[e]][d]   (agg pre-initialized)
// One thread per (edge, dim). Consecutive lanes cover consecutive dims of the
// SAME edge -> edge index is wave-uniform (scalar load) and atomic addresses
// are lane-contiguous (coalescable at TCC). Do not "vectorize" this: float4
// per-thread makes atomic lanes 16B-strided and quadruples HBM write traffic
// (measured round 2: 1.28 GB writes, 1084 us vs ~200 us this layout).
// ---------------------------------------------------------------------------
template <int DIM>
__global__ void scatter_add_kernel(const float* __restrict__ x,
                                   const int* __restrict__ src,
                                   const int* __restrict__ dst,
                                   float* __restrict__ agg) {
    const long total = (long)N_EDGES * DIM;
    for (long i = blockIdx.x * (long)blockDim.x + threadIdx.x; i < total;
         i += (long)gridDim.x * blockDim.x) {
        const int e = (int)(i / DIM);
        const int d = (int)(i - (long)e * DIM);
        atomicAdd(&agg[(long)dst[e] * DIM + d], x[(long)src[e] * DIM + d]);
    }
}

// ---------------------------------------------------------------------------
// GIN MLP: out = relu( relu(in @ wa + ba) @ wb + bb ),  in: N_NODES x K0
// Optional second output (out2) receives the same values: used to initialize
// the next layer's aggregation buffer, replacing a 25.6MB D2D memcpy.
// ---------------------------------------------------------------------------
template <int K0, int NB, bool DUAL>
__global__ void gin_mlp_kernel(const float* __restrict__ in,
                               const float* __restrict__ wa, const float* __restrict__ ba,
                               const float* __restrict__ wb, const float* __restrict__ bb,
                               float* __restrict__ out, float* __restrict__ out2) {
    __shared__ float s_in[NB][K0];
    __shared__ float s_mid[NB][HIDDEN];
    const int d  = threadIdx.x;          // 0..127
    const int n0 = blockIdx.x * NB;

    for (int idx = threadIdx.x; idx < NB * K0; idx += blockDim.x) {
        const int i = idx / K0;
        const int k = idx - i * K0;
        const int n = n0 + i;
        s_in[i][k] = (n < N_NODES) ? in[(long)n * K0 + k] : 0.f;
    }
    __syncthreads();

    float acc[NB];
    {
        const float bias = ba[d];
        #pragma unroll
        for (int i = 0; i < NB; ++i) acc[i] = bias;
        for (int k = 0; k < K0; ++k) {
            const float w = wa[k * HIDDEN + d];
            #pragma unroll
            for (int i = 0; i < NB; ++i) acc[i] += s_in[i][k] * w;
        }
        #pragma unroll
        for (int i = 0; i < NB; ++i) s_mid[i][d] = fmaxf(acc[i], 0.f);
    }
    __syncthreads();
    {
        const float bias = bb[d];
        #pragma unroll
        for (int i = 0; i < NB; ++i) acc[i] = bias;
        for (int k = 0; k < HIDDEN; ++k) {
            const float w = wb[k * HIDDEN + d];
            #pragma unroll
            for (int i = 0; i < NB; ++i) acc[i] += s_mid[i][k] * w;
        }
        #pragma unroll
        for (int i = 0; i < NB; ++i) {
            const int n = n0 + i;
            if (n < N_NODES) {
                const float v = fmaxf(acc[i], 0.f);
                out[(long)n * HIDDEN + d] = v;
                if (DUAL) out2[(long)n * HIDDEN + d] = v;
            }
        }
    }
}

// ---------------------------------------------------------------------------
// Mean pooling over sorted batch ids: run-length accumulate, few atomics.
// ---------------------------------------------------------------------------
__global__ void pool_kernel(const float* __restrict__ h,
                            const int* __restrict__ batch,
                            float* __restrict__ summed,   // NUM_GRAPHS x HIDDEN
                            float* __restrict__ counts) { // NUM_GRAPHS
    const int NPB = 128;
    const int n0 = blockIdx.x * NPB;
    if (n0 >= N_NODES) return;
    const int nend = min(n0 + NPB, N_NODES);
    const int d = threadIdx.x;

    int cur = batch[n0];
    float acc = 0.f;
    int cnt = 0;
    for (int n = n0; n < nend; ++n) {
        const int g = batch[n];
        if (g != cur) {
            atomicAdd(&summed[cur * HIDDEN + d], acc);
            if (d == 0) atomicAdd(&counts[cur], (float)cnt);
            acc = 0.f; cnt = 0; cur = g;
        }
        acc += h[(long)n * HIDDEN + d];
        ++cnt;
    }
    atomicAdd(&summed[cur * HIDDEN + d], acc);
    if (d == 0) atomicAdd(&counts[cur], (float)cnt);
}

// ---------------------------------------------------------------------------
// Per-graph head: pooled -> mu, logvar, z -> hd (decoder trunk).
// ---------------------------------------------------------------------------
__global__ void head_kernel(const float* __restrict__ summed,
                            const float* __restrict__ counts,
                            const float* __restrict__ eps,
                            const float* __restrict__ wmu, const float* __restrict__ bmu,
                            const float* __restrict__ wlv, const float* __restrict__ blv,
                            const float* __restrict__ wd1, const float* __restrict__ bd1,
                            const float* __restrict__ wd2, const float* __restrict__ bd2,
                            float* __restrict__ out_mu, float* __restrict__ out_lv,
                            float* __restrict__ hd) {
    const int g = blockIdx.x;
    const int d = threadIdx.x;
    __shared__ float s_pool[HIDDEN];
    __shared__ float s_z[LATENT];
    __shared__ float s_h1[HIDDEN];

    const float cnt = fmaxf(counts[g], 1.f);
    s_pool[d] = summed[g * HIDDEN + d] / cnt;
    __syncthreads();

    if (d < LATENT) {
        float m = bmu[d], lv = blv[d];
        for (int k = 0; k < HIDDEN; ++k) {
            const float p = s_pool[k];
            m  += p * wmu[k * LATENT + d];
            lv += p * wlv[k * LATENT + d];
        }
        lv = fminf(fmaxf(lv, -5.f), 5.f);
        out_mu[g * LATENT + d] = m;
        out_lv[g * LATENT + d] = lv;
        s_z[d] = m + eps[g * LATENT + d] * expf(0.5f * lv);
    }
    __syncthreads();
    {
        float a = bd1[d];
        for (int k = 0; k < LATENT; ++k) a += s_z[k] * wd1[k * HIDDEN + d];
        s_h1[d] = fmaxf(a, 0.f);
    }
    __syncthreads();
    {
        float a = bd2[d];
        for (int k = 0; k < HIDDEN; ++k) a += s_h1[k] * wd2[k * HIDDEN + d];
        hd[g * HIDDEN + d] = a;
    }
}

// ---------------------------------------------------------------------------
// Decoder GEMM: raw[256 x N] = hd[256 x 128] @ W[128 x N] + bias
// 16 graphs per block (LDS), one output column per thread -> 16 independent
// accumulators per thread, 16 FMA per W-load.
// ---------------------------------------------------------------------------
__global__ void decoder_gemm_kernel(const float* __restrict__ hd,
                                    const float* __restrict__ W,
                                    const float* __restrict__ bias,
                                    float* __restrict__ raw, int N) {
    const int GB = 16;
    const int o  = blockIdx.x * blockDim.x + threadIdx.x;  // output column
    const int g0 = blockIdx.y * GB;
    __shared__ float s_hd[GB][HIDDEN];

    for (int idx = threadIdx.x; idx < GB * HIDDEN; idx += blockDim.x) {
        const int g = idx >> 7;
        const int k = idx & 127;
        s_hd[g][k] = hd[(long)(g0 + g) * HIDDEN + k];
    }
    __syncthreads();
    if (o >= N) return;

    float acc[GB];
    const float bv = bias[o];
    #pragma unroll
    for (int g = 0; g < GB; ++g) acc[g] = bv;

    for (int k = 0; k < HIDDEN; ++k) {
        const float w = W[(long)k * N + o];
        #pragma unroll
        for (int g = 0; g < GB; ++g) acc[g] += s_hd[g][k] * w;
    }
    #pragma unroll
    for (int g = 0; g < GB; ++g)
        raw[(long)(g0 + g) * N + o] = acc[g];
}

// ---------------------------------------------------------------------------
// adj epilogue: out = clip(0.5*(raw + raw^T), -10, 10), diag = -10.
// ---------------------------------------------------------------------------
__global__ void adj_sym_kernel(const float* __restrict__ raw,
                               float* __restrict__ out_adj) {
    const int g = blockIdx.x;
    const int tid = threadIdx.x;
    __shared__ float s_a[MAX_NODES * MAX_NODES];  // 40KB
    const float* r = raw + (long)g * MAX_NODES * MAX_NODES;

    for (int o = tid; o < MAX_NODES * MAX_NODES; o += blockDim.x) s_a[o] = r[o];
    __syncthreads();

    float* w = out_adj + (long)g * MAX_NODES * MAX_NODES;
    for (int o = tid; o < MAX_NODES * MAX_NODES; o += blockDim.x) {
        const int i = o / MAX_NODES;
        const int j = o - i * MAX_NODES;
        float v;
        if (i == j) v = -10.f;
        else        v = fminf(fmaxf(0.5f * (s_a[o] + s_a[j * MAX_NODES + i]), -10.f), 10.f);
        w[o] = v;
    }
}

// ---------------------------------------------------------------------------
// node-feature epilogue: softmax over last dim (16), one thread per (g,node).
// ---------------------------------------------------------------------------
__global__ void nf_softmax_kernel(const float* __restrict__ raw,
                                  float* __restrict__ out_nf) {
    const int idx = blockIdx.x * blockDim.x + threadIdx.x;  // (g, m)
    if (idx >= NUM_GRAPHS * MAX_NODES) return;
    const float* r = raw + (long)idx * NODE_DIM;

    float mx = -1e30f;
    #pragma unroll
    for (int d = 0; d < NODE_DIM; ++d) mx = fmaxf(mx, r[d]);
    float e[NODE_DIM];
    float s = 0.f;
    #pragma unroll
    for (int d = 0; d < NODE_DIM; ++d) { e[d] = expf(r[d] - mx); s += e[d]; }
    const float inv = 1.f / s;
    float* w = out_nf + (long)idx * NODE_DIM;
    #pragma unroll
    for (int d = 0; d < NODE_DIM; ++d) w[d] = e[d] * inv;
}

// ---------------------------------------------------------------------------
extern "C" void kernel_launch(void* const* d_in, const int* in_sizes, int n_in,
                              void* d_out, int out_size, void* d_ws, size_t ws_size,
                              hipStream_t stream) {
    const float* x    = (const float*)d_in[0];
    const int*   edge = (const int*)d_in[1];
    const int*   src  = edge;
    const int*   dst  = edge + N_EDGES;
    const int*   batch = (const int*)d_in[2];
    const float* eps  = (const float*)d_in[3];
    const float* w1a = (const float*)d_in[4],  *b1a = (const float*)d_in[5];
    const float* w1b = (const float*)d_in[6],  *b1b = (const float*)d_in[7];
    const float* w2a = (const float*)d_in[8],  *b2a = (const float*)d_in[9];
    const float* w2b = (const float*)d_in[10], *b2b = (const float*)d_in[11];
    const float* wmu = (const float*)d_in[12], *bmu = (const float*)d_in[13];
    const float* wlv = (const float*)d_in[14], *blv = (const float*)d_in[15];
    const float* wd1 = (const float*)d_in[16], *bd1 = (const float*)d_in[17];
    const float* wd2 = (const float*)d_in[18], *bd2 = (const float*)d_in[19];
    const float* wn  = (const float*)d_in[20], *bn  = (const float*)d_in[21];
    const float* we  = (const float*)d_in[22], *be  = (const float*)d_in[23];

    float* out = (float*)d_out;
    float* out_adj = out;                                                  // 2,560,000
    float* out_nf  = out + (long)NUM_GRAPHS * MAX_NODES * MAX_NODES;       // 409,600
    float* out_mu  = out_nf + (long)NUM_GRAPHS * MAX_NODES * NODE_DIM;     // 16,384
    float* out_lv  = out_mu + NUM_GRAPHS * LATENT;                         // 16,384

    float* ws = (float*)d_ws;
    float* agg1   = ws;                                // 800,000
    float* h1     = agg1 + (long)N_NODES * NODE_DIM;   // 6,400,000
    float* agg2   = h1 + (long)N_NODES * HIDDEN;       // 6,400,000
    float* summed = agg2 + (long)N_NODES * HIDDEN;     // 32,768
    float* counts = summed + NUM_GRAPHS * HIDDEN;      // 256
    float* hd     = counts + NUM_GRAPHS;               // 32,768
    float* h2     = h1;    // reuse: h1 dead once agg2 built
    float* raw_adj = agg2; // reuse: agg2 dead after gin_mlp2  (2,560,000)
    float* raw_nf  = agg2 + (long)NUM_GRAPHS * MAX_NODES * MAX_NODES; // 409,600

    // ---- GIN layer 1 ----
    hipMemcpyAsync(agg1, x, sizeof(float) * (size_t)N_NODES * NODE_DIM,
                   hipMemcpyDeviceToDevice, stream);
    scatter_add_kernel<NODE_DIM><<<2048, 256, 0, stream>>>(x, src, dst, agg1);
    gin_mlp_kernel<NODE_DIM, 8, true><<<(N_NODES + 7) / 8, 128, 0, stream>>>(
        agg1, w1a, b1a, w1b, b1b, h1, agg2);   // dual-write: h1 and agg2 init

    // ---- GIN layer 2 ----
    scatter_add_kernel<HIDDEN><<<2048, 256, 0, stream>>>(h1, src, dst, agg2);
    gin_mlp_kernel<HIDDEN, 8, false><<<(N_NODES + 7) / 8, 128, 0, stream>>>(
        agg2, w2a, b2a, w2b, b2b, h2, nullptr);

    // ---- mean pool ----
    hipMemsetAsync(summed, 0, sizeof(float) * (NUM_GRAPHS * HIDDEN + NUM_GRAPHS), stream);
    pool_kernel<<<(N_NODES + 127) / 128, 128, 0, stream>>>(h2, batch, summed, counts);

    // ---- heads + reparam + decoder trunk ----
    head_kernel<<<NUM_GRAPHS, 128, 0, stream>>>(summed, counts, eps,
                                                wmu, bmu, wlv, blv,
                                                wd1, bd1, wd2, bd2,
                                                out_mu, out_lv, hd);

    // ---- decoder GEMMs ----
    {
        dim3 grid_adj((MAX_NODES * MAX_NODES + 255) / 256, NUM_GRAPHS / 16);
        decoder_gemm_kernel<<<grid_adj, 256, 0, stream>>>(hd, we, be, raw_adj,
                                                          MAX_NODES * MAX_NODES);
        dim3 grid_nf((MAX_NODES * NODE_DIM + 255) / 256, NUM_GRAPHS / 16);
        decoder_gemm_kernel<<<grid_nf, 256, 0, stream>>>(hd, wn, bn, raw_nf,
                                                         MAX_NODES * NODE_DIM);
    }

    // ---- epilogues ----
    adj_sym_kernel<<<NUM_GRAPHS, 512, 0, stream>>>(raw_adj, out_adj);
    nf_softmax_kernel<<<(NUM_GRAPHS * MAX_NODES + 255) / 256, 256, 0, stream>>>(
        raw_nf, out_nf);
}

// Round 4
// 402.689 us; speedup vs baseline: 3.3635x; 1.3281x over previous
//
#include <hip/hip_runtime.h>
#include <hip/hip_bf16.h>

#define N_NODES   50000
#define N_EDGES   640000
#define NODE_DIM  16
#define HIDDEN    128
#define LATENT    64
#define MAX_NODES 100
#define NUM_GRAPHS 256

// ===========================================================================
// CSR build (by dst). Replaces fp32 scatter-atomics with int histogram +
// scan + fill; the aggregation itself becomes a read-only gather (round 3:
// fp atomics write through the non-coherent per-XCD L2 -> 327MB of HBM-side
// RMW, 271us. Gather is L2-cacheable and write-free.)
// ===========================================================================
__global__ void degree_kernel(const int* __restrict__ dst, int* __restrict__ deg) {
    const int i = blockIdx.x * blockDim.x + threadIdx.x;
    if (i < N_EDGES) atomicAdd(&deg[dst[i]], 1);
}

// Single-block exclusive scan over 50000 degrees -> row_start[50001], cursor.
__global__ void scan_kernel(const int* __restrict__ deg,
                            int* __restrict__ row_start,
                            int* __restrict__ cursor) {
    __shared__ int s_wave[16];
    __shared__ int s_off;
    __shared__ int s_total;
    const int tid  = threadIdx.x;
    const int lane = tid & 63;
    const int wid  = tid >> 6;
    if (tid == 0) s_off = 0;
    __syncthreads();

    for (int base = 0; base < N_NODES; base += 1024) {
        const int idx = base + tid;
        const int v = (idx < N_NODES) ? deg[idx] : 0;
        // inclusive scan within wave
        int x = v;
        #pragma unroll
        for (int o = 1; o < 64; o <<= 1) {
            const int y = __shfl_up(x, o);
            if (lane >= o) x += y;
        }
        if (lane == 63) s_wave[wid] = x;
        __syncthreads();
        if (tid == 0) {
            int run = 0;
            #pragma unroll
            for (int w = 0; w < 16; ++w) { const int t = s_wave[w]; s_wave[w] = run; run += t; }
            s_total = run;
        }
        __syncthreads();
        const int excl = s_off + s_wave[wid] + x - v;
        if (idx < N_NODES) { row_start[idx] = excl; cursor[idx] = excl; }
        __syncthreads();
        if (tid == 0) s_off += s_total;
        __syncthreads();
    }
    if (tid == 0) row_start[N_NODES] = s_off;
}

__global__ void csr_fill_kernel(const int* __restrict__ src,
                                const int* __restrict__ dst,
                                int* __restrict__ cursor,
                                int* __restrict__ nbr) {
    const int i = blockIdx.x * blockDim.x + threadIdx.x;
    if (i < N_EDGES) {
        const int pos = atomicAdd(&cursor[dst[i]], 1);
        nbr[pos] = src[i];
    }
}

// ===========================================================================
// Fused GIN layer 1: gather(x, 16-dim) + 2-layer MLP. 8 nodes/block,
// 128 threads (= 8 groups x 16 dims for the gather, 128 output dims for MLP).
// 50000 % 8 == 0, no bounds checks.
// ===========================================================================
__global__ void gin1_fused_kernel(const float* __restrict__ in,
                                  const int* __restrict__ row_start,
                                  const int* __restrict__ nbr,
                                  const float* __restrict__ wa, const float* __restrict__ ba,
                                  const float* __restrict__ wb, const float* __restrict__ bb,
                                  float* __restrict__ out) {
    __shared__ float s_in[8][NODE_DIM];
    __shared__ float s_mid[8][HIDDEN];
    const int tid = threadIdx.x;
    const int n0  = blockIdx.x * 8;

    {   // gather: group g = node, lane k = dim
        const int grp = tid >> 4;
        const int k   = tid & 15;
        const int n   = n0 + grp;
        float acc = in[(long)n * NODE_DIM + k];
        const int beg = row_start[n], end = row_start[n + 1];
        for (int p = beg; p < end; ++p)
            acc += in[(long)nbr[p] * NODE_DIM + k];
        s_in[grp][k] = acc;
    }
    __syncthreads();

    const int d = tid;
    float acc[8];
    {
        const float bias = ba[d];
        #pragma unroll
        for (int i = 0; i < 8; ++i) acc[i] = bias;
        for (int k = 0; k < NODE_DIM; ++k) {
            const float w = wa[k * HIDDEN + d];
            #pragma unroll
            for (int i = 0; i < 8; ++i) acc[i] += s_in[i][k] * w;
        }
        #pragma unroll
        for (int i = 0; i < 8; ++i) s_mid[i][d] = fmaxf(acc[i], 0.f);
    }
    __syncthreads();
    {
        const float bias = bb[d];
        #pragma unroll
        for (int i = 0; i < 8; ++i) acc[i] = bias;
        for (int k = 0; k < HIDDEN; ++k) {
            const float w = wb[k * HIDDEN + d];
            #pragma unroll
            for (int i = 0; i < 8; ++i) acc[i] += s_mid[i][k] * w;
        }
        #pragma unroll
        for (int i = 0; i < 8; ++i)
            out[(long)(n0 + i) * HIDDEN + d] = fmaxf(acc[i], 0.f);
    }
}

// ===========================================================================
// Fused GIN layer 2: gather(h1, 128-dim) + 2-layer MLP. 8 nodes/block,
// 128 threads = one per dim; per node one coalesced 512B row read per edge.
// ===========================================================================
__global__ void gin2_fused_kernel(const float* __restrict__ in,
                                  const int* __restrict__ row_start,
                                  const int* __restrict__ nbr,
                                  const float* __restrict__ wa, const float* __restrict__ ba,
                                  const float* __restrict__ wb, const float* __restrict__ bb,
                                  float* __restrict__ out) {
    __shared__ float s_in[8][HIDDEN];
    __shared__ float s_mid[8][HIDDEN];
    const int d  = threadIdx.x;
    const int n0 = blockIdx.x * 8;

    #pragma unroll
    for (int i = 0; i < 8; ++i) {
        const int n = n0 + i;
        float acc = in[(long)n * HIDDEN + d];
        const int beg = row_start[n], end = row_start[n + 1];
        for (int p = beg; p < end; ++p)
            acc += in[(long)nbr[p] * HIDDEN + d];
        s_in[i][d] = acc;
    }
    __syncthreads();

    float acc[8];
    {
        const float bias = ba[d];
        #pragma unroll
        for (int i = 0; i < 8; ++i) acc[i] = bias;
        for (int k = 0; k < HIDDEN; ++k) {
            const float w = wa[k * HIDDEN + d];
            #pragma unroll
            for (int i = 0; i < 8; ++i) acc[i] += s_in[i][k] * w;
        }
        #pragma unroll
        for (int i = 0; i < 8; ++i) s_mid[i][d] = fmaxf(acc[i], 0.f);
    }
    __syncthreads();
    {
        const float bias = bb[d];
        #pragma unroll
        for (int i = 0; i < 8; ++i) acc[i] = bias;
        for (int k = 0; k < HIDDEN; ++k) {
            const float w = wb[k * HIDDEN + d];
            #pragma unroll
            for (int i = 0; i < 8; ++i) acc[i] += s_mid[i][k] * w;
        }
        #pragma unroll
        for (int i = 0; i < 8; ++i)
            out[(long)(n0 + i) * HIDDEN + d] = fmaxf(acc[i], 0.f);
    }
}

// ---------------------------------------------------------------------------
// Mean pooling over sorted batch ids: run-length accumulate, few atomics.
// ---------------------------------------------------------------------------
__global__ void pool_kernel(const float* __restrict__ h,
                            const int* __restrict__ batch,
                            float* __restrict__ summed,
                            float* __restrict__ counts) {
    const int NPB = 128;
    const int n0 = blockIdx.x * NPB;
    if (n0 >= N_NODES) return;
    const int nend = min(n0 + NPB, N_NODES);
    const int d = threadIdx.x;

    int cur = batch[n0];
    float acc = 0.f;
    int cnt = 0;
    for (int n = n0; n < nend; ++n) {
        const int g = batch[n];
        if (g != cur) {
            atomicAdd(&summed[cur * HIDDEN + d], acc);
            if (d == 0) atomicAdd(&counts[cur], (float)cnt);
            acc = 0.f; cnt = 0; cur = g;
        }
        acc += h[(long)n * HIDDEN + d];
        ++cnt;
    }
    atomicAdd(&summed[cur * HIDDEN + d], acc);
    if (d == 0) atomicAdd(&counts[cur], (float)cnt);
}

// ---------------------------------------------------------------------------
// Per-graph head: pooled -> mu, logvar, z -> hd (decoder trunk).
// ---------------------------------------------------------------------------
__global__ void head_kernel(const float* __restrict__ summed,
                            const float* __restrict__ counts,
                            const float* __restrict__ eps,
                            const float* __restrict__ wmu, const float* __restrict__ bmu,
                            const float* __restrict__ wlv, const float* __restrict__ blv,
                            const float* __restrict__ wd1, const float* __restrict__ bd1,
                            const float* __restrict__ wd2, const float* __restrict__ bd2,
                            float* __restrict__ out_mu, float* __restrict__ out_lv,
                            float* __restrict__ hd) {
    const int g = blockIdx.x;
    const int d = threadIdx.x;
    __shared__ float s_pool[HIDDEN];
    __shared__ float s_z[LATENT];
    __shared__ float s_h1[HIDDEN];

    const float cnt = fmaxf(counts[g], 1.f);
    s_pool[d] = summed[g * HIDDEN + d] / cnt;
    __syncthreads();

    if (d < LATENT) {
        float m = bmu[d], lv = blv[d];
        for (int k = 0; k < HIDDEN; ++k) {
            const float p = s_pool[k];
            m  += p * wmu[k * LATENT + d];
            lv += p * wlv[k * LATENT + d];
        }
        lv = fminf(fmaxf(lv, -5.f), 5.f);
        out_mu[g * LATENT + d] = m;
        out_lv[g * LATENT + d] = lv;
        s_z[d] = m + eps[g * LATENT + d] * expf(0.5f * lv);
    }
    __syncthreads();
    {
        float a = bd1[d];
        for (int k = 0; k < LATENT; ++k) a += s_z[k] * wd1[k * HIDDEN + d];
        s_h1[d] = fmaxf(a, 0.f);
    }
    __syncthreads();
    {
        float a = bd2[d];
        for (int k = 0; k < HIDDEN; ++k) a += s_h1[k] * wd2[k * HIDDEN + d];
        hd[g * HIDDEN + d] = a;
    }
}

// ---------------------------------------------------------------------------
// Decoder GEMM: raw[256 x N] = hd[256 x 128] @ W[128 x N] + bias
// ---------------------------------------------------------------------------
__global__ void decoder_gemm_kernel(const float* __restrict__ hd,
                                    const float* __restrict__ W,
                                    const float* __restrict__ bias,
                                    float* __restrict__ raw, int N) {
    const int GB = 16;
    const int o  = blockIdx.x * blockDim.x + threadIdx.x;
    const int g0 = blockIdx.y * GB;
    __shared__ float s_hd[GB][HIDDEN];

    for (int idx = threadIdx.x; idx < GB * HIDDEN; idx += blockDim.x) {
        const int g = idx >> 7;
        const int k = idx & 127;
        s_hd[g][k] = hd[(long)(g0 + g) * HIDDEN + k];
    }
    __syncthreads();
    if (o >= N) return;

    float acc[GB];
    const float bv = bias[o];
    #pragma unroll
    for (int g = 0; g < GB; ++g) acc[g] = bv;

    for (int k = 0; k < HIDDEN; ++k) {
        const float w = W[(long)k * N + o];
        #pragma unroll
        for (int g = 0; g < GB; ++g) acc[g] += s_hd[g][k] * w;
    }
    #pragma unroll
    for (int g = 0; g < GB; ++g)
        raw[(long)(g0 + g) * N + o] = acc[g];
}

// ---------------------------------------------------------------------------
// adj epilogue: out = clip(0.5*(raw + raw^T), -10, 10), diag = -10.
// ---------------------------------------------------------------------------
__global__ void adj_sym_kernel(const float* __restrict__ raw,
                               float* __restrict__ out_adj) {
    const int g = blockIdx.x;
    const int tid = threadIdx.x;
    __shared__ float s_a[MAX_NODES * MAX_NODES];
    const float* r = raw + (long)g * MAX_NODES * MAX_NODES;

    for (int o = tid; o < MAX_NODES * MAX_NODES; o += blockDim.x) s_a[o] = r[o];
    __syncthreads();

    float* w = out_adj + (long)g * MAX_NODES * MAX_NODES;
    for (int o = tid; o < MAX_NODES * MAX_NODES; o += blockDim.x) {
        const int i = o / MAX_NODES;
        const int j = o - i * MAX_NODES;
        float v;
        if (i == j) v = -10.f;
        else        v = fminf(fmaxf(0.5f * (s_a[o] + s_a[j * MAX_NODES + i]), -10.f), 10.f);
        w[o] = v;
    }
}

// ---------------------------------------------------------------------------
// node-feature epilogue: softmax over last dim (16).
// ---------------------------------------------------------------------------
__global__ void nf_softmax_kernel(const float* __restrict__ raw,
                                  float* __restrict__ out_nf) {
    const int idx = blockIdx.x * blockDim.x + threadIdx.x;
    if (idx >= NUM_GRAPHS * MAX_NODES) return;
    const float* r = raw + (long)idx * NODE_DIM;

    float mx = -1e30f;
    #pragma unroll
    for (int d = 0; d < NODE_DIM; ++d) mx = fmaxf(mx, r[d]);
    float e[NODE_DIM];
    float s = 0.f;
    #pragma unroll
    for (int d = 0; d < NODE_DIM; ++d) { e[d] = expf(r[d] - mx); s += e[d]; }
    const float inv = 1.f / s;
    float* w = out_nf + (long)idx * NODE_DIM;
    #pragma unroll
    for (int d = 0; d < NODE_DIM; ++d) w[d] = e[d] * inv;
}

// ---------------------------------------------------------------------------
extern "C" void kernel_launch(void* const* d_in, const int* in_sizes, int n_in,
                              void* d_out, int out_size, void* d_ws, size_t ws_size,
                              hipStream_t stream) {
    const float* x    = (const float*)d_in[0];
    const int*   edge = (const int*)d_in[1];
    const int*   src  = edge;
    const int*   dst  = edge + N_EDGES;
    const int*   batch = (const int*)d_in[2];
    const float* eps  = (const float*)d_in[3];
    const float* w1a = (const float*)d_in[4],  *b1a = (const float*)d_in[5];
    const float* w1b = (const float*)d_in[6],  *b1b = (const float*)d_in[7];
    const float* w2a = (const float*)d_in[8],  *b2a = (const float*)d_in[9];
    const float* w2b = (const float*)d_in[10], *b2b = (const float*)d_in[11];
    const float* wmu = (const float*)d_in[12], *bmu = (const float*)d_in[13];
    const float* wlv = (const float*)d_in[14], *blv = (const float*)d_in[15];
    const float* wd1 = (const float*)d_in[16], *bd1 = (const float*)d_in[17];
    const float* wd2 = (const float*)d_in[18], *bd2 = (const float*)d_in[19];
    const float* wn  = (const float*)d_in[20], *bn  = (const float*)d_in[21];
    const float* we  = (const float*)d_in[22], *be  = (const float*)d_in[23];

    float* out = (float*)d_out;
    float* out_adj = out;                                                  // 2,560,000
    float* out_nf  = out + (long)NUM_GRAPHS * MAX_NODES * MAX_NODES;       // 409,600
    float* out_mu  = out_nf + (long)NUM_GRAPHS * MAX_NODES * NODE_DIM;     // 16,384
    float* out_lv  = out_mu + NUM_GRAPHS * LATENT;                         // 16,384

    float* ws = (float*)d_ws;
    float* h1     = ws;                               // 6,400,000 floats
    float* h2     = h1 + (long)N_NODES * HIDDEN;      // 6,400,000 floats
    float* summed = h2 + (long)N_NODES * HIDDEN;      // 32,768
    float* counts = summed + NUM_GRAPHS * HIDDEN;     // 256
    float* hd     = counts + NUM_GRAPHS;              // 32,768
    int*   ibase  = (int*)(hd + NUM_GRAPHS * HIDDEN);
    int*   deg       = ibase;                         // 50,000 ints
    int*   row_start = deg + N_NODES;                 // 50,001 ints
    int*   cursor    = row_start + N_NODES + 1;       // 50,000 ints
    int*   nbr       = cursor + N_NODES;              // 640,000 ints
    // raw decoder buffers reuse h1 (dead after gin2)
    float* raw_adj = h1;                                              // 2,560,000
    float* raw_nf  = h1 + (long)NUM_GRAPHS * MAX_NODES * MAX_NODES;   // 409,600

    // ---- CSR build ----
    hipMemsetAsync(deg, 0, sizeof(int) * N_NODES, stream);
    degree_kernel<<<(N_EDGES + 255) / 256, 256, 0, stream>>>(dst, deg);
    scan_kernel<<<1, 1024, 0, stream>>>(deg, row_start, cursor);
    csr_fill_kernel<<<(N_EDGES + 255) / 256, 256, 0, stream>>>(src, dst, cursor, nbr);

    // ---- GIN layers (fused gather + MLP) ----
    gin1_fused_kernel<<<N_NODES / 8, 128, 0, stream>>>(x, row_start, nbr,
                                                       w1a, b1a, w1b, b1b, h1);
    gin2_fused_kernel<<<N_NODES / 8, 128, 0, stream>>>(h1, row_start, nbr,
                                                       w2a, b2a, w2b, b2b, h2);

    // ---- mean pool ----
    hipMemsetAsync(summed, 0, sizeof(float) * (NUM_GRAPHS * HIDDEN + NUM_GRAPHS), stream);
    pool_kernel<<<(N_NODES + 127) / 128, 128, 0, stream>>>(h2, batch, summed, counts);

    // ---- heads + reparam + decoder trunk ----
    head_kernel<<<NUM_GRAPHS, 128, 0, stream>>>(summed, counts, eps,
                                                wmu, bmu, wlv, blv,
                                                wd1, bd1, wd2, bd2,
                                                out_mu, out_lv, hd);

    // ---- decoder GEMMs (raw buffers alias h1, dead after gin2) ----
    {
        dim3 grid_adj((MAX_NODES * MAX_NODES + 255) / 256, NUM_GRAPHS / 16);
        decoder_gemm_kernel<<<grid_adj, 256, 0, stream>>>(hd, we, be, raw_adj,
                                                          MAX_NODES * MAX_NODES);
        dim3 grid_nf((MAX_NODES * NODE_DIM + 255) / 256, NUM_GRAPHS / 16);
        decoder_gemm_kernel<<<grid_nf, 256, 0, stream>>>(hd, wn, bn, raw_nf,
                                                         MAX_NODES * NODE_DIM);
    }

    // ---- epilogues ----
    adj_sym_kernel<<<NUM_GRAPHS, 512, 0, stream>>>(raw_adj, out_adj);
    nf_softmax_kernel<<<(NUM_GRAPHS * MAX_NODES + 255) / 256, 256, 0, stream>>>(
        raw_nf, out_nf);
}

// Round 5
// 390.389 us; speedup vs baseline: 3.4695x; 1.0315x over previous
//
#include <hip/hip_runtime.h>
#include <hip/hip_bf16.h>

#define N_NODES   50000
#define N_EDGES   640000
#define NODE_DIM  16
#define HIDDEN    128
#define LATENT    64
#define MAX_NODES 100
#define NUM_GRAPHS 256

// ===========================================================================
// CSR build (by dst). Gather replaces fp32 scatter-atomics (round 3: fp
// atomics bypass non-coherent L2 -> 327MB HBM RMW, 271us).
// ===========================================================================
__global__ void degree_kernel(const int* __restrict__ dst, int* __restrict__ deg) {
    const int i = blockIdx.x * blockDim.x + threadIdx.x;
    if (i < N_EDGES) atomicAdd(&deg[dst[i]], 1);
}

__global__ void scan_kernel(const int* __restrict__ deg,
                            int* __restrict__ row_start,
                            int* __restrict__ cursor) {
    __shared__ int s_wave[16];
    __shared__ int s_off;
    __shared__ int s_total;
    const int tid  = threadIdx.x;
    const int lane = tid & 63;
    const int wid  = tid >> 6;
    if (tid == 0) s_off = 0;
    __syncthreads();

    for (int base = 0; base < N_NODES; base += 1024) {
        const int idx = base + tid;
        const int v = (idx < N_NODES) ? deg[idx] : 0;
        int x = v;
        #pragma unroll
        for (int o = 1; o < 64; o <<= 1) {
            const int y = __shfl_up(x, o);
            if (lane >= o) x += y;
        }
        if (lane == 63) s_wave[wid] = x;
        __syncthreads();
        if (tid == 0) {
            int run = 0;
            #pragma unroll
            for (int w = 0; w < 16; ++w) { const int t = s_wave[w]; s_wave[w] = run; run += t; }
            s_total = run;
        }
        __syncthreads();
        const int excl = s_off + s_wave[wid] + x - v;
        if (idx < N_NODES) { row_start[idx] = excl; cursor[idx] = excl; }
        __syncthreads();
        if (tid == 0) s_off += s_total;
        __syncthreads();
    }
    if (tid == 0) row_start[N_NODES] = s_off;
}

__global__ void csr_fill_kernel(const int* __restrict__ src,
                                const int* __restrict__ dst,
                                int* __restrict__ cursor,
                                int* __restrict__ nbr) {
    const int i = blockIdx.x * blockDim.x + threadIdx.x;
    if (i < N_EDGES) {
        const int pos = atomicAdd(&cursor[dst[i]], 1);
        nbr[pos] = src[i];
    }
}

// ===========================================================================
// Fused GIN layer 1: gather(x,16) + MLP(16->128->128). 16 nodes/block,
// 128 threads. Gather: 8 groups x 16 dims, 2 nodes/group, 4-acc ILP
// (explicit partial sums break the fp add chain -> 4 loads in flight).
// MLP: 4x4 register tile per thread (4 nodes x 4 dims): per k-step
// 4 ds_read_b32 + 1 float4 weight load + 16 FMA (round 4: thread-per-dim
// did 16 ds_read per k -> LDS-issue-bound at VALUBusy 47%).
// ===========================================================================
__global__ void gin1_fused_kernel(const float* __restrict__ in,
                                  const int* __restrict__ row_start,
                                  const int* __restrict__ nbr,
                                  const float* __restrict__ wa, const float* __restrict__ ba,
                                  const float* __restrict__ wb, const float* __restrict__ bb,
                                  float* __restrict__ out) {
    __shared__ float s_in[16][NODE_DIM + 1];   // pad: stride 17
    __shared__ float s_mid[16][HIDDEN + 4];    // pad: stride 132 (16B-aligned rows)
    const int tid = threadIdx.x;
    const int n0  = blockIdx.x * 16;

    {   // gather
        const int grp = tid >> 4;   // 0..7
        const int k   = tid & 15;
        #pragma unroll
        for (int half = 0; half < 2; ++half) {
            const int i = grp + half * 8;
            const int n = n0 + i;
            const int beg = row_start[n], end = row_start[n + 1];
            float a0 = in[(long)n * NODE_DIM + k], a1 = 0.f, a2 = 0.f, a3 = 0.f;
            int p = beg;
            for (; p + 4 <= end; p += 4) {
                const int e0 = nbr[p], e1 = nbr[p + 1], e2 = nbr[p + 2], e3 = nbr[p + 3];
                a0 += in[(long)e0 * NODE_DIM + k];
                a1 += in[(long)e1 * NODE_DIM + k];
                a2 += in[(long)e2 * NODE_DIM + k];
                a3 += in[(long)e3 * NODE_DIM + k];
            }
            for (; p < end; ++p) a0 += in[(long)nbr[p] * NODE_DIM + k];
            s_in[i][k] = (a0 + a1) + (a2 + a3);
        }
    }
    __syncthreads();

    const int dq = tid & 31;  const int d0 = dq * 4;
    const int iq = tid >> 5;  const int i0 = iq * 4;
    float acc[4][4];

    {   // layer A (K=16)
        const float4 bv = *(const float4*)&ba[d0];
        #pragma unroll
        for (int j = 0; j < 4; ++j) {
            acc[j][0] = bv.x; acc[j][1] = bv.y; acc[j][2] = bv.z; acc[j][3] = bv.w;
        }
        for (int k = 0; k < NODE_DIM; ++k) {
            const float4 w = *(const float4*)&wa[k * HIDDEN + d0];
            #pragma unroll
            for (int j = 0; j < 4; ++j) {
                const float a = s_in[i0 + j][k];
                acc[j][0] += a * w.x; acc[j][1] += a * w.y;
                acc[j][2] += a * w.z; acc[j][3] += a * w.w;
            }
        }
        #pragma unroll
        for (int j = 0; j < 4; ++j) {
            float4 v;
            v.x = fmaxf(acc[j][0], 0.f); v.y = fmaxf(acc[j][1], 0.f);
            v.z = fmaxf(acc[j][2], 0.f); v.w = fmaxf(acc[j][3], 0.f);
            *(float4*)&s_mid[i0 + j][d0] = v;
        }
    }
    __syncthreads();
    {   // layer B (K=128)
        const float4 bv = *(const float4*)&bb[d0];
        #pragma unroll
        for (int j = 0; j < 4; ++j) {
            acc[j][0] = bv.x; acc[j][1] = bv.y; acc[j][2] = bv.z; acc[j][3] = bv.w;
        }
        for (int k = 0; k < HIDDEN; ++k) {
            const float4 w = *(const float4*)&wb[k * HIDDEN + d0];
            #pragma unroll
            for (int j = 0; j < 4; ++j) {
                const float a = s_mid[i0 + j][k];
                acc[j][0] += a * w.x; acc[j][1] += a * w.y;
                acc[j][2] += a * w.z; acc[j][3] += a * w.w;
            }
        }
        #pragma unroll
        for (int j = 0; j < 4; ++j) {
            float4 v;
            v.x = fmaxf(acc[j][0], 0.f); v.y = fmaxf(acc[j][1], 0.f);
            v.z = fmaxf(acc[j][2], 0.f); v.w = fmaxf(acc[j][3], 0.f);
            *(float4*)&out[(long)(n0 + i0 + j) * HIDDEN + d0] = v;
        }
    }
}

// ===========================================================================
// Fused GIN layer 2: gather(h1,128) + MLP(128->128->128). Same structure;
// gather is thread-per-dim (128 dims), 16 sequential nodes, 4-acc ILP.
// ===========================================================================
__global__ void gin2_fused_kernel(const float* __restrict__ in,
                                  const int* __restrict__ row_start,
                                  const int* __restrict__ nbr,
                                  const float* __restrict__ wa, const float* __restrict__ ba,
                                  const float* __restrict__ wb, const float* __restrict__ bb,
                                  float* __restrict__ out) {
    __shared__ float s_in[16][HIDDEN + 1];     // stride 129
    __shared__ float s_mid[16][HIDDEN + 4];    // stride 132
    const int tid = threadIdx.x;
    const int n0  = blockIdx.x * 16;

    {   // gather: d = tid
        const int d = tid;
        for (int i = 0; i < 16; ++i) {
            const int n = n0 + i;
            const int beg = row_start[n], end = row_start[n + 1];
            float a0 = in[(long)n * HIDDEN + d], a1 = 0.f, a2 = 0.f, a3 = 0.f;
            int p = beg;
            for (; p + 4 <= end; p += 4) {
                const int e0 = nbr[p], e1 = nbr[p + 1], e2 = nbr[p + 2], e3 = nbr[p + 3];
                a0 += in[(long)e0 * HIDDEN + d];
                a1 += in[(long)e1 * HIDDEN + d];
                a2 += in[(long)e2 * HIDDEN + d];
                a3 += in[(long)e3 * HIDDEN + d];
            }
            for (; p < end; ++p) a0 += in[(long)nbr[p] * HIDDEN + d];
            s_in[i][d] = (a0 + a1) + (a2 + a3);
        }
    }
    __syncthreads();

    const int dq = tid & 31;  const int d0 = dq * 4;
    const int iq = tid >> 5;  const int i0 = iq * 4;
    float acc[4][4];

    {   // layer A
        const float4 bv = *(const float4*)&ba[d0];
        #pragma unroll
        for (int j = 0; j < 4; ++j) {
            acc[j][0] = bv.x; acc[j][1] = bv.y; acc[j][2] = bv.z; acc[j][3] = bv.w;
        }
        for (int k = 0; k < HIDDEN; ++k) {
            const float4 w = *(const float4*)&wa[k * HIDDEN + d0];
            #pragma unroll
            for (int j = 0; j < 4; ++j) {
                const float a = s_in[i0 + j][k];
                acc[j][0] += a * w.x; acc[j][1] += a * w.y;
                acc[j][2] += a * w.z; acc[j][3] += a * w.w;
            }
        }
        #pragma unroll
        for (int j = 0; j < 4; ++j) {
            float4 v;
            v.x = fmaxf(acc[j][0], 0.f); v.y = fmaxf(acc[j][1], 0.f);
            v.z = fmaxf(acc[j][2], 0.f); v.w = fmaxf(acc[j][3], 0.f);
            *(float4*)&s_mid[i0 + j][d0] = v;
        }
    }
    __syncthreads();
    {   // layer B
        const float4 bv = *(const float4*)&bb[d0];
        #pragma unroll
        for (int j = 0; j < 4; ++j) {
            acc[j][0] = bv.x; acc[j][1] = bv.y; acc[j][2] = bv.z; acc[j][3] = bv.w;
        }
        for (int k = 0; k < HIDDEN; ++k) {
            const float4 w = *(const float4*)&wb[k * HIDDEN + d0];
            #pragma unroll
            for (int j = 0; j < 4; ++j) {
                const float a = s_mid[i0 + j][k];
                acc[j][0] += a * w.x; acc[j][1] += a * w.y;
                acc[j][2] += a * w.z; acc[j][3] += a * w.w;
            }
        }
        #pragma unroll
        for (int j = 0; j < 4; ++j) {
            float4 v;
            v.x = fmaxf(acc[j][0], 0.f); v.y = fmaxf(acc[j][1], 0.f);
            v.z = fmaxf(acc[j][2], 0.f); v.w = fmaxf(acc[j][3], 0.f);
            *(float4*)&out[(long)(n0 + i0 + j) * HIDDEN + d0] = v;
        }
    }
}

// ---------------------------------------------------------------------------
// Mean pooling over sorted batch ids: run-length accumulate, few atomics.
// ---------------------------------------------------------------------------
__global__ void pool_kernel(const float* __restrict__ h,
                            const int* __restrict__ batch,
                            float* __restrict__ summed,
                            float* __restrict__ counts) {
    const int NPB = 128;
    const int n0 = blockIdx.x * NPB;
    if (n0 >= N_NODES) return;
    const int nend = min(n0 + NPB, N_NODES);
    const int d = threadIdx.x;

    int cur = batch[n0];
    float acc = 0.f;
    int cnt = 0;
    for (int n = n0; n < nend; ++n) {
        const int g = batch[n];
        if (g != cur) {
            atomicAdd(&summed[cur * HIDDEN + d], acc);
            if (d == 0) atomicAdd(&counts[cur], (float)cnt);
            acc = 0.f; cnt = 0; cur = g;
        }
        acc += h[(long)n * HIDDEN + d];
        ++cnt;
    }
    atomicAdd(&summed[cur * HIDDEN + d], acc);
    if (d == 0) atomicAdd(&counts[cur], (float)cnt);
}

// ---------------------------------------------------------------------------
// Per-graph head: pooled -> mu, logvar, z -> hd (decoder trunk).
// ---------------------------------------------------------------------------
__global__ void head_kernel(const float* __restrict__ summed,
                            const float* __restrict__ counts,
                            const float* __restrict__ eps,
                            const float* __restrict__ wmu, const float* __restrict__ bmu,
                            const float* __restrict__ wlv, const float* __restrict__ blv,
                            const float* __restrict__ wd1, const float* __restrict__ bd1,
                            const float* __restrict__ wd2, const float* __restrict__ bd2,
                            float* __restrict__ out_mu, float* __restrict__ out_lv,
                            float* __restrict__ hd) {
    const int g = blockIdx.x;
    const int d = threadIdx.x;
    __shared__ float s_pool[HIDDEN];
    __shared__ float s_z[LATENT];
    __shared__ float s_h1[HIDDEN];

    const float cnt = fmaxf(counts[g], 1.f);
    s_pool[d] = summed[g * HIDDEN + d] / cnt;
    __syncthreads();

    if (d < LATENT) {
        float m = bmu[d], lv = blv[d];
        for (int k = 0; k < HIDDEN; ++k) {
            const float p = s_pool[k];
            m  += p * wmu[k * LATENT + d];
            lv += p * wlv[k * LATENT + d];
        }
        lv = fminf(fmaxf(lv, -5.f), 5.f);
        out_mu[g * LATENT + d] = m;
        out_lv[g * LATENT + d] = lv;
        s_z[d] = m + eps[g * LATENT + d] * expf(0.5f * lv);
    }
    __syncthreads();
    {
        float a = bd1[d];
        for (int k = 0; k < LATENT; ++k) a += s_z[k] * wd1[k * HIDDEN + d];
        s_h1[d] = fmaxf(a, 0.f);
    }
    __syncthreads();
    {
        float a = bd2[d];
        for (int k = 0; k < HIDDEN; ++k) a += s_h1[k] * wd2[k * HIDDEN + d];
        hd[g * HIDDEN + d] = a;
    }
}

// ---------------------------------------------------------------------------
// Decoder GEMM: raw[256 x N] = hd[256 x 128] @ W[128 x N] + bias
// ---------------------------------------------------------------------------
__global__ void decoder_gemm_kernel(const float* __restrict__ hd,
                                    const float* __restrict__ W,
                                    const float* __restrict__ bias,
                                    float* __restrict__ raw, int N) {
    const int GB = 16;
    const int o  = blockIdx.x * blockDim.x + threadIdx.x;
    const int g0 = blockIdx.y * GB;
    __shared__ float s_hd[GB][HIDDEN];

    for (int idx = threadIdx.x; idx < GB * HIDDEN; idx += blockDim.x) {
        const int g = idx >> 7;
        const int k = idx & 127;
        s_hd[g][k] = hd[(long)(g0 + g) * HIDDEN + k];
    }
    __syncthreads();
    if (o >= N) return;

    float acc[GB];
    const float bv = bias[o];
    #pragma unroll
    for (int g = 0; g < GB; ++g) acc[g] = bv;

    for (int k = 0; k < HIDDEN; ++k) {
        const float w = W[(long)k * N + o];
        #pragma unroll
        for (int g = 0; g < GB; ++g) acc[g] += s_hd[g][k] * w;
    }
    #pragma unroll
    for (int g = 0; g < GB; ++g)
        raw[(long)(g0 + g) * N + o] = acc[g];
}

// ---------------------------------------------------------------------------
// adj epilogue: out = clip(0.5*(raw + raw^T), -10, 10), diag = -10.
// ---------------------------------------------------------------------------
__global__ void adj_sym_kernel(const float* __restrict__ raw,
                               float* __restrict__ out_adj) {
    const int g = blockIdx.x;
    const int tid = threadIdx.x;
    __shared__ float s_a[MAX_NODES * MAX_NODES];
    const float* r = raw + (long)g * MAX_NODES * MAX_NODES;

    for (int o = tid; o < MAX_NODES * MAX_NODES; o += blockDim.x) s_a[o] = r[o];
    __syncthreads();

    float* w = out_adj + (long)g * MAX_NODES * MAX_NODES;
    for (int o = tid; o < MAX_NODES * MAX_NODES; o += blockDim.x) {
        const int i = o / MAX_NODES;
        const int j = o - i * MAX_NODES;
        float v;
        if (i == j) v = -10.f;
        else        v = fminf(fmaxf(0.5f * (s_a[o] + s_a[j * MAX_NODES + i]), -10.f), 10.f);
        w[o] = v;
    }
}

// ---------------------------------------------------------------------------
// node-feature epilogue: softmax over last dim (16).
// ---------------------------------------------------------------------------
__global__ void nf_softmax_kernel(const float* __restrict__ raw,
                                  float* __restrict__ out_nf) {
    const int idx = blockIdx.x * blockDim.x + threadIdx.x;
    if (idx >= NUM_GRAPHS * MAX_NODES) return;
    const float* r = raw + (long)idx * NODE_DIM;

    float mx = -1e30f;
    #pragma unroll
    for (int d = 0; d < NODE_DIM; ++d) mx = fmaxf(mx, r[d]);
    float e[NODE_DIM];
    float s = 0.f;
    #pragma unroll
    for (int d = 0; d < NODE_DIM; ++d) { e[d] = expf(r[d] - mx); s += e[d]; }
    const float inv = 1.f / s;
    float* w = out_nf + (long)idx * NODE_DIM;
    #pragma unroll
    for (int d = 0; d < NODE_DIM; ++d) w[d] = e[d] * inv;
}

// ---------------------------------------------------------------------------
extern "C" void kernel_launch(void* const* d_in, const int* in_sizes, int n_in,
                              void* d_out, int out_size, void* d_ws, size_t ws_size,
                              hipStream_t stream) {
    const float* x    = (const float*)d_in[0];
    const int*   edge = (const int*)d_in[1];
    const int*   src  = edge;
    const int*   dst  = edge + N_EDGES;
    const int*   batch = (const int*)d_in[2];
    const float* eps  = (const float*)d_in[3];
    const float* w1a = (const float*)d_in[4],  *b1a = (const float*)d_in[5];
    const float* w1b = (const float*)d_in[6],  *b1b = (const float*)d_in[7];
    const float* w2a = (const float*)d_in[8],  *b2a = (const float*)d_in[9];
    const float* w2b = (const float*)d_in[10], *b2b = (const float*)d_in[11];
    const float* wmu = (const float*)d_in[12], *bmu = (const float*)d_in[13];
    const float* wlv = (const float*)d_in[14], *blv = (const float*)d_in[15];
    const float* wd1 = (const float*)d_in[16], *bd1 = (const float*)d_in[17];
    const float* wd2 = (const float*)d_in[18], *bd2 = (const float*)d_in[19];
    const float* wn  = (const float*)d_in[20], *bn  = (const float*)d_in[21];
    const float* we  = (const float*)d_in[22], *be  = (const float*)d_in[23];

    float* out = (float*)d_out;
    float* out_adj = out;                                                  // 2,560,000
    float* out_nf  = out + (long)NUM_GRAPHS * MAX_NODES * MAX_NODES;       // 409,600
    float* out_mu  = out_nf + (long)NUM_GRAPHS * MAX_NODES * NODE_DIM;     // 16,384
    float* out_lv  = out_mu + NUM_GRAPHS * LATENT;                         // 16,384

    float* ws = (float*)d_ws;
    float* h1     = ws;                               // 6,400,000 floats
    float* h2     = h1 + (long)N_NODES * HIDDEN;      // 6,400,000 floats
    float* summed = h2 + (long)N_NODES * HIDDEN;      // 32,768
    float* counts = summed + NUM_GRAPHS * HIDDEN;     // 256
    float* hd     = counts + NUM_GRAPHS;              // 32,768
    int*   ibase  = (int*)(hd + NUM_GRAPHS * HIDDEN);
    int*   deg       = ibase;                         // 50,000 ints
    int*   row_start = deg + N_NODES;                 // 50,001 ints
    int*   cursor    = row_start + N_NODES + 1;       // 50,000 ints
    int*   nbr       = cursor + N_NODES;              // 640,000 ints
    float* raw_adj = h1;                                              // reuse
    float* raw_nf  = h1 + (long)NUM_GRAPHS * MAX_NODES * MAX_NODES;

    // ---- CSR build ----
    hipMemsetAsync(deg, 0, sizeof(int) * N_NODES, stream);
    degree_kernel<<<(N_EDGES + 255) / 256, 256, 0, stream>>>(dst, deg);
    scan_kernel<<<1, 1024, 0, stream>>>(deg, row_start, cursor);
    csr_fill_kernel<<<(N_EDGES + 255) / 256, 256, 0, stream>>>(src, dst, cursor, nbr);

    // ---- GIN layers (fused gather + MLP) ----
    gin1_fused_kernel<<<N_NODES / 16, 128, 0, stream>>>(x, row_start, nbr,
                                                        w1a, b1a, w1b, b1b, h1);
    gin2_fused_kernel<<<N_NODES / 16, 128, 0, stream>>>(h1, row_start, nbr,
                                                        w2a, b2a, w2b, b2b, h2);

    // ---- mean pool ----
    hipMemsetAsync(summed, 0, sizeof(float) * (NUM_GRAPHS * HIDDEN + NUM_GRAPHS), stream);
    pool_kernel<<<(N_NODES + 127) / 128, 128, 0, stream>>>(h2, batch, summed, counts);

    // ---- heads + reparam + decoder trunk ----
    head_kernel<<<NUM_GRAPHS, 128, 0, stream>>>(summed, counts, eps,
                                                wmu, bmu, wlv, blv,
                                                wd1, bd1, wd2, bd2,
                                                out_mu, out_lv, hd);

    // ---- decoder GEMMs ----
    {
        dim3 grid_adj((MAX_NODES * MAX_NODES + 255) / 256, NUM_GRAPHS / 16);
        decoder_gemm_kernel<<<grid_adj, 256, 0, stream>>>(hd, we, be, raw_adj,
                                                          MAX_NODES * MAX_NODES);
        dim3 grid_nf((MAX_NODES * NODE_DIM + 255) / 256, NUM_GRAPHS / 16);
        decoder_gemm_kernel<<<grid_nf, 256, 0, stream>>>(hd, wn, bn, raw_nf,
                                                         MAX_NODES * NODE_DIM);
    }

    // ---- epilogues ----
    adj_sym_kernel<<<NUM_GRAPHS, 512, 0, stream>>>(raw_adj, out_adj);
    nf_softmax_kernel<<<(NUM_GRAPHS * MAX_NODES + 255) / 256, 256, 0, stream>>>(
        raw_nf, out_nf);
}